// Round 1
// baseline (2389.789 us; speedup 1.0000x reference)
//
#include <hip/hip_runtime.h>
#include <math.h>

#define HID 64
#define NG 256          // 4*H gates
#define NBATCH 1024
#define TLEN 512

__device__ __forceinline__ float sigmoidf_(float x) {
    return 1.0f / (1.0f + __expf(-x));
}
__device__ __forceinline__ float tanhf_(float x) {
    // 2*sigmoid(2x)-1 ; saturates correctly for large |x|
    return 2.0f / (1.0f + __expf(-2.0f * x)) - 1.0f;
}

// Persistent per-chunk LSTM layer scan.
// Block: 256 threads, owns 4 batch elements for tc timesteps.
// thread t: bh = t>>7 selects batch pair {2bh, 2bh+1}; gid = t&127 -> gates gid, gid+128.
// Weights (Wih|Whh concatenated along k, K = KIN+64) stored in LDS transposed as
// wt[kc][g][0..3] (float4 over k) so weight reads are conflict-free ds_read_b128
// and activation reads are wave-uniform float4 broadcasts.
template<int KIN>
__global__ __launch_bounds__(256, 1) void lstm_layer(
    const float* __restrict__ Wih,   // [256][KIN]
    const float* __restrict__ Whh,   // [256][64]
    const float* __restrict__ bih,
    const float* __restrict__ bhh,
    const float* __restrict__ in,    // [B][.][KIN], row stride in_bstride, time origin in_t0
    long in_bstride,
    int in_t0,
    float* __restrict__ hseq,        // [B][tc][64] h output sequence, or nullptr
    float* __restrict__ hstate,      // [B][64] persistent h across chunks
    float* __restrict__ cstate,      // [B][64] persistent c across chunks
    int t0, int tc)
{
    constexpr int K  = KIN + HID;
    constexpr int KC = K / 4;

    __shared__ __align__(16) float wt[KC * 1024];   // [kc][g][4]
    __shared__ float bias_s[NG];
    __shared__ __align__(16) float act[4][K];       // per-batch input row: [x_t | h]
    __shared__ float gact[4][NG];                   // activated gates
    __shared__ float cbuf[4][HID];

    const int tid = threadIdx.x;
    const int bg0 = blockIdx.x * 4;   // first global batch index of this block

    // ---- one-time: load + transpose weights into LDS ----
    for (int idx = tid; idx < NG * K; idx += 256) {
        int g = idx / K;
        int k = idx - g * K;
        float v = (k < KIN) ? Wih[g * KIN + k] : Whh[g * HID + (k - KIN)];
        wt[(k >> 2) * 1024 + g * 4 + (k & 3)] = v;
    }
    bias_s[tid] = bih[tid] + bhh[tid];
    {
        int b = tid >> 6, j = tid & 63;
        float h0 = 0.0f, c0 = 0.0f;
        if (t0 > 0) {
            h0 = hstate[(bg0 + b) * HID + j];
            c0 = cstate[(bg0 + b) * HID + j];
        }
        act[b][KIN + j] = h0;
        cbuf[b][j]      = c0;
    }
    __syncthreads();

    const int gid  = tid & 127;
    const int bh   = tid >> 7;       // 0 or 1: which batch pair
    const int b0   = 2 * bh, b1 = 2 * bh + 1;
    const float bias0 = bias_s[gid];
    const float bias1 = bias_s[gid + 128];
    const bool  isG   = (gid < 64);  // gate gid+128 is 'g' (tanh) else 'o' (sigmoid)
    const int ub = tid >> 6, uj = tid & 63;   // (batch, hidden) for the update phase

    const float4* w4 = (const float4*)wt;

    for (int t = t0; t < t0 + tc; ++t) {
        // ---- phase 1: load this step's input slice into act[.][0..KIN) ----
        if (KIN == 32) {
            if (tid < 128) {
                int b = tid >> 5, k = tid & 31;
                act[b][k] = in[(long)(bg0 + b) * in_bstride + (long)(t - in_t0) * KIN + k];
            }
        } else {
            int b = tid >> 6, k = tid & 63;
            act[b][k] = in[(long)(bg0 + b) * in_bstride + (long)(t - in_t0) * KIN + k];
        }
        __syncthreads();

        // ---- phase 2: gates = [x|h] . W^T  (2 gates x 2 batches per thread) ----
        float a00 = 0.f, a01 = 0.f, a10 = 0.f, a11 = 0.f;
        const float4* A0 = (const float4*)act[b0];
        const float4* A1 = (const float4*)act[b1];
        #pragma unroll
        for (int kc = 0; kc < KC; ++kc) {
            float4 w0 = w4[kc * 256 + gid];
            float4 w1 = w4[kc * 256 + 128 + gid];
            float4 x0 = A0[kc];
            float4 x1 = A1[kc];
            a00 = fmaf(w0.x, x0.x, a00); a00 = fmaf(w0.y, x0.y, a00);
            a00 = fmaf(w0.z, x0.z, a00); a00 = fmaf(w0.w, x0.w, a00);
            a01 = fmaf(w0.x, x1.x, a01); a01 = fmaf(w0.y, x1.y, a01);
            a01 = fmaf(w0.z, x1.z, a01); a01 = fmaf(w0.w, x1.w, a01);
            a10 = fmaf(w1.x, x0.x, a10); a10 = fmaf(w1.y, x0.y, a10);
            a10 = fmaf(w1.z, x0.z, a10); a10 = fmaf(w1.w, x0.w, a10);
            a11 = fmaf(w1.x, x1.x, a11); a11 = fmaf(w1.y, x1.y, a11);
            a11 = fmaf(w1.z, x1.z, a11); a11 = fmaf(w1.w, x1.w, a11);
        }
        float v00 = a00 + bias0, v01 = a01 + bias0;
        float v10 = a10 + bias1, v11 = a11 + bias1;
        // gates gid in [0,128): i or f -> sigmoid
        gact[b0][gid] = sigmoidf_(v00);
        gact[b1][gid] = sigmoidf_(v01);
        if (isG) {
            gact[b0][gid + 128] = tanhf_(v10);
            gact[b1][gid + 128] = tanhf_(v11);
        } else {
            gact[b0][gid + 128] = sigmoidf_(v10);
            gact[b1][gid + 128] = sigmoidf_(v11);
        }
        __syncthreads();

        // ---- phase 3: state update, each thread one (batch, j) ----
        {
            float iv = gact[ub][uj];
            float fv = gact[ub][64 + uj];
            float gv = gact[ub][128 + uj];
            float ov = gact[ub][192 + uj];
            float c  = fmaf(fv, cbuf[ub][uj], iv * gv);
            cbuf[ub][uj] = c;
            float h  = ov * tanhf_(c);
            act[ub][KIN + uj] = h;
            if (hseq)
                hseq[((long)(bg0 + ub) * tc + (t - t0)) * HID + uj] = h;
        }
        __syncthreads();
    }

    // ---- persist state for next chunk / FC head ----
    hstate[(bg0 + ub) * HID + uj] = act[ub][KIN + uj];
    cstate[(bg0 + ub) * HID + uj] = cbuf[ub][uj];
}

// Final FC head: out[b] = fc2( relu(fc1(h2_last)) ), one thread per batch.
__global__ __launch_bounds__(256) void fc_head(
    const float* __restrict__ h2,    // [B][64]
    const float* __restrict__ w1,    // [32][64]
    const float* __restrict__ b1,    // [32]
    const float* __restrict__ w2,    // [2][32]
    const float* __restrict__ b2,    // [2]
    float* __restrict__ out)         // [B][2]
{
    int b = blockIdx.x * 256 + threadIdx.x;   // grid covers exactly 1024
    float h[HID];
    const float4* h4 = (const float4*)(h2 + (long)b * HID);
    #pragma unroll
    for (int q = 0; q < 16; ++q) {
        float4 v = h4[q];
        h[4*q] = v.x; h[4*q+1] = v.y; h[4*q+2] = v.z; h[4*q+3] = v.w;
    }
    float o0 = b2[0], o1 = b2[1];
    for (int m = 0; m < 32; ++m) {
        float z = b1[m];
        #pragma unroll
        for (int j = 0; j < HID; ++j)
            z = fmaf(w1[m * HID + j], h[j], z);
        z = fmaxf(z, 0.0f);
        o0 = fmaf(w2[m],      z, o0);
        o1 = fmaf(w2[32 + m], z, o1);
    }
    out[(long)b * 2]     = o0;
    out[(long)b * 2 + 1] = o1;
}

extern "C" void kernel_launch(void* const* d_in, const int* in_sizes, int n_in,
                              void* d_out, int out_size, void* d_ws, size_t ws_size,
                              hipStream_t stream) {
    const float* x     = (const float*)d_in[0];
    const float* Wih0  = (const float*)d_in[1];
    const float* Whh0  = (const float*)d_in[2];
    const float* bih0  = (const float*)d_in[3];
    const float* bhh0  = (const float*)d_in[4];
    const float* Wih1  = (const float*)d_in[5];
    const float* Whh1  = (const float*)d_in[6];
    const float* bih1  = (const float*)d_in[7];
    const float* bhh1  = (const float*)d_in[8];
    const float* fc1w  = (const float*)d_in[9];
    const float* fc1b  = (const float*)d_in[10];
    const float* fc2w  = (const float*)d_in[11];
    const float* fc2b  = (const float*)d_in[12];
    float* out = (float*)d_out;

    // workspace carve: h1 chunk buffer [B][tc][64] + 4 state arrays [B][64]
    const size_t stateFloats = (size_t)NBATCH * HID;          // 65536 floats
    const size_t stateBytes  = stateFloats * 4;               // 256 KB
    int tc = TLEN;
    while (tc > 1 && ((size_t)tc * NBATCH * HID * 4 + 4 * stateBytes) > ws_size)
        tc >>= 1;

    char* ws = (char*)d_ws;
    float* h1buf = (float*)ws;
    float* hs0   = (float*)(ws + (size_t)tc * NBATCH * HID * 4);
    float* cs0   = hs0 + stateFloats;
    float* hs1   = cs0 + stateFloats;
    float* cs1   = hs1 + stateFloats;

    dim3 grid(NBATCH / 4), block(256);
    for (int t0 = 0; t0 < TLEN; t0 += tc) {
        lstm_layer<32><<<grid, block, 0, stream>>>(
            Wih0, Whh0, bih0, bhh0,
            x, (long)TLEN * 32, 0,
            h1buf, hs0, cs0, t0, tc);
        lstm_layer<64><<<grid, block, 0, stream>>>(
            Wih1, Whh1, bih1, bhh1,
            h1buf, (long)tc * HID, t0,
            nullptr, hs1, cs1, t0, tc);
    }
    fc_head<<<dim3(NBATCH / 256), block, 0, stream>>>(hs1, fc1w, fc1b, fc2w, fc2b, out);
}

// Round 2
// 1984.498 us; speedup vs baseline: 1.2042x; 1.2042x over previous
//
#include <hip/hip_runtime.h>
#include <math.h>

#define HID 64
#define TLEN 512
#define NB 1024
#define AS 160   // act stride (floats) per batch: [x 0:32 | h1 32:96 | h2 96:160]

__device__ __forceinline__ float dpp_quad_sum(float v) {
    // butterfly sum over each group of 4 lanes; all 4 lanes get the same value
    int i = __float_as_int(v);
    v += __int_as_float(__builtin_amdgcn_update_dpp(0, i, 0xB1, 0xF, 0xF, true)); // quad_perm [1,0,3,2]
    i = __float_as_int(v);
    v += __int_as_float(__builtin_amdgcn_update_dpp(0, i, 0x4E, 0xF, 0xF, true)); // quad_perm [2,3,0,1]
    return v;
}
__device__ __forceinline__ float sigmoidf_(float x) { return 1.0f / (1.0f + __expf(-x)); }
__device__ __forceinline__ float tanhf_(float x)    { return 2.0f / (1.0f + __expf(-2.0f * x)) - 1.0f; }

#define FMA4(acc, wrow, i4, v)                  \
    acc = fmaf(wrow[(i4)*4+0], v.x, acc);       \
    acc = fmaf(wrow[(i4)*4+1], v.y, acc);       \
    acc = fmaf(wrow[(i4)*4+2], v.z, acc);       \
    acc = fmaf(wrow[(i4)*4+3], v.w, acc);

// One persistent kernel: 256 blocks x 256 threads, block owns 4 batches for all 512 steps,
// both LSTM layers fused + FC head. Weights live in VGPRs (224 f32/thread).
__global__ __launch_bounds__(256, 1) void lstm_fused(
    const float* __restrict__ x,      // [1024][512][32]
    const float* __restrict__ Wih0, const float* __restrict__ Whh0,
    const float* __restrict__ bih0, const float* __restrict__ bhh0,
    const float* __restrict__ Wih1, const float* __restrict__ Whh1,
    const float* __restrict__ bih1, const float* __restrict__ bhh1,
    const float* __restrict__ fc1w, const float* __restrict__ fc1b,
    const float* __restrict__ fc2w, const float* __restrict__ fc2b,
    float* __restrict__ out)          // [1024][2]
{
    __shared__ __align__(16) float act[4 * AS];
    __shared__ float zbuf[4][32];

    const int tid = threadIdx.x;
    const int q   = tid & 3;    // K-quarter
    const int gg  = tid >> 2;   // hidden unit 0..63
    const int bg0 = blockIdx.x * 4;

    // ---- one-time: weights for my 4 gates, my K-quarter, into registers ----
    // L0: K=96 ([x(32)|h1(64)]), quarter = 24 values. L1: K=128 ([h1|h2]), quarter = 32 values.
    // L1 weights stored PRE-ROTATED (chunk order (i4+2q)&7) so LDS reads are bank-disjoint
    // across q while register indices stay compile-time constant.
    float W0[4][24];
    float W1[4][32];
    float bs0[4], bs1[4];
    #pragma unroll
    for (int u = 0; u < 4; ++u) {
        const int g = gg + 64 * u;
        bs0[u] = bih0[g] + bhh0[g];
        bs1[u] = bih1[g] + bhh1[g];
        #pragma unroll
        for (int i = 0; i < 24; ++i) {
            int k = q * 24 + i;                       // 0..95
            W0[u][i] = (k < 32) ? Wih0[g * 32 + k] : Whh0[g * 64 + (k - 32)];
        }
        #pragma unroll
        for (int i4 = 0; i4 < 8; ++i4) {
            int kq = (((i4 + 2 * q) & 7)) * 4;        // rotated chunk within quarter
            #pragma unroll
            for (int j = 0; j < 4; ++j) {
                int k = q * 32 + kq + j;              // 0..127
                W1[u][i4 * 4 + j] = (k < 64) ? Wih1[g * 64 + k] : Whh1[g * 64 + (k - 64)];
            }
        }
    }

    // ---- init LDS act (h1,h2 = 0) and c-state ----
    for (int idx = tid; idx < 4 * AS; idx += 256) act[idx] = 0.0f;
    float c0[4] = {0.f, 0.f, 0.f, 0.f};
    float c1[4] = {0.f, 0.f, 0.f, 0.f};
    __syncthreads();

    // ---- x loader lanes: threads 0..31, (xb = batch, xc = float4 chunk of 8) ----
    const bool xldr = (tid < 32);
    const int  xb = tid >> 3, xc = tid & 7;
    const float4* x4 = (const float4*)x;
    float4 xnext = make_float4(0.f, 0.f, 0.f, 0.f);
    if (xldr) {
        float4 v0 = x4[((long)(bg0 + xb) * TLEN + 0) * 8 + xc];
        ((float4*)&act[xb * AS])[xc] = v0;
        xnext = x4[((long)(bg0 + xb) * TLEN + 1) * 8 + xc];
    }
    __syncthreads();

    for (int t = 0; t < TLEN; ++t) {
        // ================= layer 0 gates: K = 96, 6 float4 chunks =================
        float s0[4][4];
        {
            float4 xa[6], xn[6];
            const float4* A0 = (const float4*)&act[q * 24];
            #pragma unroll
            for (int i4 = 0; i4 < 6; ++i4) xa[i4] = A0[i4];
            #pragma unroll
            for (int b = 0; b < 4; ++b) {
                if (b < 3) {
                    const float4* An = (const float4*)&act[(b + 1) * AS + q * 24];
                    #pragma unroll
                    for (int i4 = 0; i4 < 6; ++i4) xn[i4] = An[i4];
                }
                float a0 = 0.f, a1 = 0.f, a2 = 0.f, a3 = 0.f;
                #pragma unroll
                for (int i4 = 0; i4 < 6; ++i4) {
                    float4 v = xa[i4];
                    FMA4(a0, W0[0], i4, v)
                    FMA4(a1, W0[1], i4, v)
                    FMA4(a2, W0[2], i4, v)
                    FMA4(a3, W0[3], i4, v)
                }
                s0[b][0] = a0; s0[b][1] = a1; s0[b][2] = a2; s0[b][3] = a3;
                if (b < 3) {
                    #pragma unroll
                    for (int i4 = 0; i4 < 6; ++i4) xa[i4] = xn[i4];
                }
            }
        }
        // quad-reduce + activations + c0 update (pure registers, before barrier)
        float h1w = 0.f;
        #pragma unroll
        for (int b = 0; b < 4; ++b) {
            float iv = sigmoidf_(dpp_quad_sum(s0[b][0]) + bs0[0]);
            float fv = sigmoidf_(dpp_quad_sum(s0[b][1]) + bs0[1]);
            float gv = tanhf_  (dpp_quad_sum(s0[b][2]) + bs0[2]);
            float ov = sigmoidf_(dpp_quad_sum(s0[b][3]) + bs0[3]);
            float c  = fmaf(fv, c0[b], iv * gv);
            c0[b] = c;
            float h = ov * tanhf_(c);
            if (b == q) h1w = h;    // lane writes batch q only
        }
        __syncthreads();   // all L0 reads done

        // publish x[t+1] and h1[t]
        if (xldr) ((float4*)&act[xb * AS])[xc] = xnext;
        act[q * AS + 32 + gg] = h1w;
        __syncthreads();   // h1 visible

        // ================= layer 1 gates: K = 128, 8 float4 chunks (q-rotated) =================
        float s1[4][4];
        {
            float4 xa[8], xn[8];
            const int ro = 2 * q;
            const float* A1 = &act[32 + q * 32];
            #pragma unroll
            for (int i4 = 0; i4 < 8; ++i4)
                xa[i4] = *(const float4*)(A1 + ((i4 + ro) & 7) * 4);
            #pragma unroll
            for (int b = 0; b < 4; ++b) {
                if (b < 3) {
                    const float* An = &act[(b + 1) * AS + 32 + q * 32];
                    #pragma unroll
                    for (int i4 = 0; i4 < 8; ++i4)
                        xn[i4] = *(const float4*)(An + ((i4 + ro) & 7) * 4);
                }
                float a0 = 0.f, a1 = 0.f, a2 = 0.f, a3 = 0.f;
                #pragma unroll
                for (int i4 = 0; i4 < 8; ++i4) {
                    float4 v = xa[i4];
                    FMA4(a0, W1[0], i4, v)
                    FMA4(a1, W1[1], i4, v)
                    FMA4(a2, W1[2], i4, v)
                    FMA4(a3, W1[3], i4, v)
                }
                s1[b][0] = a0; s1[b][1] = a1; s1[b][2] = a2; s1[b][3] = a3;
                if (b < 3) {
                    #pragma unroll
                    for (int i4 = 0; i4 < 8; ++i4) xa[i4] = xn[i4];
                }
            }
        }
        float h2w = 0.f;
        #pragma unroll
        for (int b = 0; b < 4; ++b) {
            float iv = sigmoidf_(dpp_quad_sum(s1[b][0]) + bs1[0]);
            float fv = sigmoidf_(dpp_quad_sum(s1[b][1]) + bs1[1]);
            float gv = tanhf_  (dpp_quad_sum(s1[b][2]) + bs1[2]);
            float ov = sigmoidf_(dpp_quad_sum(s1[b][3]) + bs1[3]);
            float c  = fmaf(fv, c1[b], iv * gv);
            c1[b] = c;
            float h = ov * tanhf_(c);
            if (b == q) h2w = h;
        }
        __syncthreads();   // all L1 reads done

        act[q * AS + 96 + gg] = h2w;           // h2[t]; ordered vs next-step L1 reads by next barriers
        if (xldr) {                             // prefetch x[t+2]
            int tn = (t + 2 < TLEN) ? (t + 2) : (TLEN - 1);
            xnext = x4[((long)(bg0 + xb) * TLEN + tn) * 8 + xc];
        }
        // no barrier here: h2 region is only read by next step's L1 kloop,
        // which is preceded by two barriers.
    }
    __syncthreads();   // final h2 visible for FC head

    // ================= FC head =================
    if (tid < 128) {
        int b = tid >> 5, m = tid & 31;
        float z = fc1b[m];
        #pragma unroll
        for (int j = 0; j < HID; ++j)
            z = fmaf(fc1w[m * HID + j], act[b * AS + 96 + j], z);
        zbuf[b][m] = fmaxf(z, 0.0f);
    }
    __syncthreads();
    if (tid < 8) {
        int b = tid >> 1, o = tid & 1;
        float s = fc2b[o];
        #pragma unroll
        for (int m = 0; m < 32; ++m)
            s = fmaf(fc2w[o * 32 + m], zbuf[b][m], s);
        out[(long)(bg0 + b) * 2 + o] = s;
    }
}

extern "C" void kernel_launch(void* const* d_in, const int* in_sizes, int n_in,
                              void* d_out, int out_size, void* d_ws, size_t ws_size,
                              hipStream_t stream) {
    const float* x    = (const float*)d_in[0];
    const float* Wih0 = (const float*)d_in[1];
    const float* Whh0 = (const float*)d_in[2];
    const float* bih0 = (const float*)d_in[3];
    const float* bhh0 = (const float*)d_in[4];
    const float* Wih1 = (const float*)d_in[5];
    const float* Whh1 = (const float*)d_in[6];
    const float* bih1 = (const float*)d_in[7];
    const float* bhh1 = (const float*)d_in[8];
    const float* fc1w = (const float*)d_in[9];
    const float* fc1b = (const float*)d_in[10];
    const float* fc2w = (const float*)d_in[11];
    const float* fc2b = (const float*)d_in[12];
    float* out = (float*)d_out;

    lstm_fused<<<dim3(NB / 4), dim3(256), 0, stream>>>(
        x, Wih0, Whh0, bih0, bhh0, Wih1, Whh1, bih1, bhh1,
        fc1w, fc1b, fc2w, fc2b, out);
}

// Round 3
// 573.659 us; speedup vs baseline: 4.1659x; 3.4594x over previous
//
#include <hip/hip_runtime.h>
#include <math.h>

#define TLEN 512
#define NB   1024
#define BPB  16           // batches per block
#define AS   168          // f16 act row stride (336B: 16B-aligned, bank-balanced)
#define GS   260          // f32 gact row stride (1040B: 16B-aligned)

typedef _Float16 f16;
typedef f16   f16x8 __attribute__((ext_vector_type(8)));
typedef float f32x4 __attribute__((ext_vector_type(4)));

__device__ __forceinline__ float fast_rcp(float v) { return __builtin_amdgcn_rcpf(v); }
__device__ __forceinline__ float tanh_full(float v) {
    float e = __expf(-2.0f * v);
    return 2.0f * fast_rcp(1.0f + e) - 1.0f;
}

// act LDS layout per batch row: k 0..31 = x_t | 32..95 = h1 | 96..159 = h2  (f16)
// Wave w computes gate rows [16w,16w+16) of gates=[i|f|g|o] (64 each) for all 16 batches.
// MFMA frag maps: A row = lane&15, k = (lane>>4)*8+i ; B col = lane&15, same k;
// D col = lane&15, row = (lane>>4)*4 + r.
__global__ __launch_bounds__(1024, 1) void lstm_mfma(
    const float* __restrict__ x,
    const float* __restrict__ Wih0, const float* __restrict__ Whh0,
    const float* __restrict__ bih0, const float* __restrict__ bhh0,
    const float* __restrict__ Wih1, const float* __restrict__ Whh1,
    const float* __restrict__ bih1, const float* __restrict__ bhh1,
    const float* __restrict__ fc1w, const float* __restrict__ fc1b,
    const float* __restrict__ fc2w, const float* __restrict__ fc2b,
    float* __restrict__ out)
{
    __shared__ __align__(16) f16   act[BPB * AS];
    __shared__ __align__(16) float gact0[BPB * GS];
    __shared__ __align__(16) float gact1[BPB * GS];
    __shared__ float zbuf[BPB][33];

    const int tid  = threadIdx.x;
    const int lane = tid & 63;
    const int w    = tid >> 6;        // wave 0..15
    const int bcol = lane & 15;       // MFMA col (batch) / A row (gate within tile)
    const int lq   = lane >> 4;       // k-octet / D-row quad
    const int bg0  = blockIdx.x * BPB;

    // ---- one-time: weight A-fragments into registers ----
    f16x8 A0[3], A1[4];
    float bias0v[4], bias1v[4];
    {
        const int gr = 16 * w + bcol;             // A-fragment gate row
        #pragma unroll
        for (int s = 0; s < 3; ++s) {
            #pragma unroll
            for (int i = 0; i < 8; ++i) {
                int k = 32 * s + lq * 8 + i;      // K=96: [x(32)|h1(64)]
                float v = (k < 32) ? Wih0[gr * 32 + k] : Whh0[gr * 64 + (k - 32)];
                A0[s][i] = (f16)v;
            }
        }
        #pragma unroll
        for (int s = 0; s < 4; ++s) {
            #pragma unroll
            for (int i = 0; i < 8; ++i) {
                int k = 32 * s + lq * 8 + i;      // K=128: [h1(64)|h2(64)]
                float v = (k < 64) ? Wih1[gr * 64 + k] : Whh1[gr * 64 + (k - 64)];
                A1[s][i] = (f16)v;
            }
        }
        #pragma unroll
        for (int r = 0; r < 4; ++r) {
            int gd = 16 * w + lq * 4 + r;         // D-row gate index
            bias0v[r] = bih0[gd] + bhh0[gd];
            bias1v[r] = bih1[gd] + bhh1[gd];
        }
    }
    // gate type is wave-uniform: waves 0-3=i,4-7=f (sigmoid), 8-11=g (tanh), 12-15=o
    const bool  isTanhWave = ((w >> 2) == 2);
    const float aScale = isTanhWave ? 2.0f : 1.0f;   // act = a*rcp(1+exp(-a*v)) - (a-1)
    const float aOff   = aScale - 1.0f;

    for (int idx = tid; idx < BPB * AS; idx += 1024) act[idx] = (f16)0;
    float c0 = 0.0f, c1 = 0.0f;
    __syncthreads();

    // ---- x staging: wave 0 writes x[0], prefetches x[1] into regs ----
    float4 xcur0, xcur1;
    if (w == 0) {
        const float* xp = x + ((long)(bg0 + bcol) * TLEN) * 32 + lq * 8;
        float4 a = *(const float4*)xp;
        float4 b = *(const float4*)(xp + 4);
        f16x8 xv;
        xv[0]=(f16)a.x; xv[1]=(f16)a.y; xv[2]=(f16)a.z; xv[3]=(f16)a.w;
        xv[4]=(f16)b.x; xv[5]=(f16)b.y; xv[6]=(f16)b.z; xv[7]=(f16)b.w;
        *(f16x8*)(act + bcol * AS + lq * 8) = xv;
        xcur0 = *(const float4*)(xp + 32);
        xcur1 = *(const float4*)(xp + 36);
    }
    __syncthreads();

    f16*        actB = act + bcol * AS + lq * 8;             // B-frag base (k-octet)
    float*      g0w  = gact0 + bcol * GS + 16 * w + lq * 4;  // gate write base
    float*      g1w  = gact1 + bcol * GS + 16 * w + lq * 4;
    const float* g0r = gact0 + w * GS + lane;                // c-update read base (batch w)
    const float* g1r = gact1 + w * GS + lane;

    #pragma unroll 1
    for (int t = 0; t < TLEN; ++t) {
        // ======== P1: layer-0 gates (K=96, 3 MFMA) ========
        f16x8 b0 = *(const f16x8*)(actB);
        f16x8 b1 = *(const f16x8*)(actB + 32);
        f16x8 b2 = *(const f16x8*)(actB + 64);
        f32x4 acc = {0.f, 0.f, 0.f, 0.f};
        acc = __builtin_amdgcn_mfma_f32_16x16x32_f16(A0[0], b0, acc, 0, 0, 0);
        acc = __builtin_amdgcn_mfma_f32_16x16x32_f16(A0[1], b1, acc, 0, 0, 0);
        acc = __builtin_amdgcn_mfma_f32_16x16x32_f16(A0[2], b2, acc, 0, 0, 0);
        f32x4 gv;
        #pragma unroll
        for (int r = 0; r < 4; ++r) {
            float v = acc[r] + bias0v[r];
            float e = __expf(-aScale * v);
            gv[r] = aScale * fast_rcp(1.0f + e) - aOff;
        }
        *(f32x4*)g0w = gv;
        __syncthreads();   // BAR A: gact0 visible; all L0 act-reads done

        // ======== P2: c-update L0 (wave w = batch w) + publish x[t+1] ========
        {
            float iv = g0r[0], fv = g0r[64], ggv = g0r[128], ov = g0r[192];
            c0 = fmaf(fv, c0, iv * ggv);
            float h = ov * tanh_full(c0);
            act[w * AS + 32 + lane] = (f16)h;       // h1[t]
        }
        if (w == 0) {
            f16x8 xv;                                // x[t+1] (loaded a full step ago)
            xv[0]=(f16)xcur0.x; xv[1]=(f16)xcur0.y; xv[2]=(f16)xcur0.z; xv[3]=(f16)xcur0.w;
            xv[4]=(f16)xcur1.x; xv[5]=(f16)xcur1.y; xv[6]=(f16)xcur1.z; xv[7]=(f16)xcur1.w;
            *(f16x8*)actB = xv;
            int tn = (t + 2 < TLEN) ? (t + 2) : (TLEN - 1);  // prefetch x[t+2]
            const float* xp = x + ((long)(bg0 + bcol) * TLEN + tn) * 32 + lq * 8;
            xcur0 = *(const float4*)xp;
            xcur1 = *(const float4*)(xp + 4);
        }
        __syncthreads();   // BAR B: h1[t] + x[t+1] visible

        // ======== P3: layer-1 gates (K=128, 4 MFMA) ========
        f16x8 d0 = *(const f16x8*)(actB + 32);
        f16x8 d1 = *(const f16x8*)(actB + 64);
        f16x8 d2 = *(const f16x8*)(actB + 96);
        f16x8 d3 = *(const f16x8*)(actB + 128);
        acc = (f32x4){0.f, 0.f, 0.f, 0.f};
        acc = __builtin_amdgcn_mfma_f32_16x16x32_f16(A1[0], d0, acc, 0, 0, 0);
        acc = __builtin_amdgcn_mfma_f32_16x16x32_f16(A1[1], d1, acc, 0, 0, 0);
        acc = __builtin_amdgcn_mfma_f32_16x16x32_f16(A1[2], d2, acc, 0, 0, 0);
        acc = __builtin_amdgcn_mfma_f32_16x16x32_f16(A1[3], d3, acc, 0, 0, 0);
        #pragma unroll
        for (int r = 0; r < 4; ++r) {
            float v = acc[r] + bias1v[r];
            float e = __expf(-aScale * v);
            gv[r] = aScale * fast_rcp(1.0f + e) - aOff;
        }
        *(f32x4*)g1w = gv;
        __syncthreads();   // BAR C: gact1 visible; all L1 act-reads (h2[t-1]) done

        // ======== P4: c-update L1 ========
        {
            float iv = g1r[0], fv = g1r[64], ggv = g1r[128], ov = g1r[192];
            c1 = fmaf(fv, c1, iv * ggv);
            float h = ov * tanh_full(c1);
            act[w * AS + 96 + lane] = (f16)h;       // h2[t]
        }
        // no barrier: h2[t]'s first reader (next P3) is behind next BAR A+B;
        // next P1 touches only x/h1 regions and gact0.
    }
    __syncthreads();

    // ======== FC head ========
    if (tid < 512) {
        int b = tid >> 5, m = tid & 31;
        float z = fc1b[m];
        #pragma unroll
        for (int j = 0; j < 64; ++j)
            z = fmaf(fc1w[m * 64 + j], (float)act[b * AS + 96 + j], z);
        zbuf[b][m] = fmaxf(z, 0.0f);
    }
    __syncthreads();
    if (tid < 32) {
        int b = tid >> 1, o = tid & 1;
        float s = fc2b[o];
        #pragma unroll
        for (int m = 0; m < 32; ++m)
            s = fmaf(fc2w[o * 32 + m], zbuf[b][m], s);
        out[(long)(bg0 + b) * 2 + o] = s;
    }
}

extern "C" void kernel_launch(void* const* d_in, const int* in_sizes, int n_in,
                              void* d_out, int out_size, void* d_ws, size_t ws_size,
                              hipStream_t stream) {
    const float* x    = (const float*)d_in[0];
    const float* Wih0 = (const float*)d_in[1];
    const float* Whh0 = (const float*)d_in[2];
    const float* bih0 = (const float*)d_in[3];
    const float* bhh0 = (const float*)d_in[4];
    const float* Wih1 = (const float*)d_in[5];
    const float* Whh1 = (const float*)d_in[6];
    const float* bih1 = (const float*)d_in[7];
    const float* bhh1 = (const float*)d_in[8];
    const float* fc1w = (const float*)d_in[9];
    const float* fc1b = (const float*)d_in[10];
    const float* fc2w = (const float*)d_in[11];
    const float* fc2b = (const float*)d_in[12];
    float* out = (float*)d_out;

    lstm_mfma<<<dim3(NB / BPB), dim3(1024), 0, stream>>>(
        x, Wih0, Whh0, bih0, bhh0, Wih1, Whh1, bih1, bhh1,
        fc1w, fc1b, fc2w, fc2b, out);
}

// Round 4
// 523.294 us; speedup vs baseline: 4.5668x; 1.0962x over previous
//
#include <hip/hip_runtime.h>
#include <math.h>

#define TLEN 512
#define NB   1024
#define XSTR 40    // xbuf row stride (f16)
#define HSTR 72    // h1/h2 row stride (f16)
#define XLAY (16 * XSTR)
#define HLAY (16 * HSTR)

typedef _Float16 f16;
typedef f16   f16x4 __attribute__((ext_vector_type(4)));
typedef f16   f16x8 __attribute__((ext_vector_type(8)));
typedef float f32x4 __attribute__((ext_vector_type(4)));

__device__ __forceinline__ float sigf(float x) {
    return __builtin_amdgcn_rcpf(1.0f + __expf(-x));
}
__device__ __forceinline__ float tanhf_(float x) {
    return 2.0f * __builtin_amdgcn_rcpf(1.0f + __expf(-2.0f * x)) - 1.0f;
}

// 256 blocks x 256 threads (4 waves). Block owns 4 batches (MFMA cols 0..3; cols 4..15 zero).
// Wave w computes, per layer, 4 MFMA tiles = gates {i,f,g,o} for hidden units 16w..16w+15.
// After the 4 acc chains, lane (lq=lane>>4, bc=lane&15) holds ALL FOUR gates of
// (hidden 16w+lq*4+r, batch bc) in regs -> cell update is pure-register, no gact LDS.
// LDS: x/h1/h2 double-buffered f16; 2 barriers/step.
__global__ __launch_bounds__(256, 1) void lstm_fused(
    const float* __restrict__ x,
    const float* __restrict__ Wih0, const float* __restrict__ Whh0,
    const float* __restrict__ bih0, const float* __restrict__ bhh0,
    const float* __restrict__ Wih1, const float* __restrict__ Whh1,
    const float* __restrict__ bih1, const float* __restrict__ bhh1,
    const float* __restrict__ fc1w, const float* __restrict__ fc1b,
    const float* __restrict__ fc2w, const float* __restrict__ fc2b,
    float* __restrict__ out)
{
    __shared__ __align__(16) f16 xbuf[2 * XLAY];
    __shared__ __align__(16) f16 h1buf[2 * HLAY];
    __shared__ __align__(16) f16 h2buf[2 * HLAY];
    __shared__ float zbuf[4][33];

    const int tid  = threadIdx.x;
    const int lane = tid & 63;
    const int w    = tid >> 6;     // wave 0..3 -> hidden group 16w..16w+15
    const int bc   = lane & 15;    // MFMA col (batch) / A-frag row-within-tile
    const int lq   = lane >> 4;    // k-octet / D-row quad
    const int bg0  = blockIdx.x * 4;

    // ---- one-time: A-fragments (per-gate tiles) + biases into registers ----
    f16x8 A0[4][3], A1[4][4];
    float bias0[4][4], bias1[4][4];
    #pragma unroll
    for (int g = 0; g < 4; ++g) {
        const int gr = g * 64 + 16 * w + bc;      // gate-matrix row for A-frag
        #pragma unroll
        for (int s = 0; s < 3; ++s)
            #pragma unroll
            for (int i = 0; i < 8; ++i) {
                int k = 32 * s + lq * 8 + i;      // K=96: [x(32)|h1(64)]
                A0[g][s][i] = (f16)((k < 32) ? Wih0[gr * 32 + k] : Whh0[gr * 64 + (k - 32)]);
            }
        #pragma unroll
        for (int s = 0; s < 4; ++s)
            #pragma unroll
            for (int i = 0; i < 8; ++i) {
                int k = 32 * s + lq * 8 + i;      // K=128: [h1(64)|h2(64)]
                A1[g][s][i] = (f16)((k < 64) ? Wih1[gr * 64 + k] : Whh1[gr * 64 + (k - 64)]);
            }
        #pragma unroll
        for (int r = 0; r < 4; ++r) {
            int gd = g * 64 + 16 * w + lq * 4 + r; // D-row gate index
            bias0[g][r] = bih0[gd] + bhh0[gd];
            bias1[g][r] = bih1[gd] + bhh1[gd];
        }
    }

    // ---- zero LDS (cols >=4 stay zero forever) ----
    for (int i = tid; i < 2 * XLAY; i += 256) xbuf[i] = (f16)0;
    for (int i = tid; i < 2 * HLAY; i += 256) { h1buf[i] = (f16)0; h2buf[i] = (f16)0; }
    __syncthreads();

    // ---- x staging: wave 3, lanes 0..31: lane = (batch 0..3) x (chunk 0..7 of float4) ----
    const bool xduty = (w == 3) && (lane < 32);
    const int  xbat = lane >> 3, xchk = lane & 7;
    const float* xg = x + ((long)(bg0 + xbat) * TLEN) * 32 + xchk * 4;
    const int xw_off = xbat * XSTR + xchk * 4;
    float4 xpre;
    if (xduty) {
        float4 v = *(const float4*)xg;            // x[0]
        f16x4 h; h[0]=(f16)v.x; h[1]=(f16)v.y; h[2]=(f16)v.z; h[3]=(f16)v.w;
        *(f16x4*)(xbuf + xw_off) = h;             // parity 0
        xpre = *(const float4*)(xg + 32);         // x[1]
    }
    __syncthreads();

    const int bcx = bc * XSTR + lq * 8;           // B-frag read offsets
    const int bch = bc * HSTR + lq * 8;
    const int hw  = bc * HSTR + 16 * w + lq * 4;  // h write offset (bc<4 only)

    float c0[4] = {0.f,0.f,0.f,0.f}, c1[4] = {0.f,0.f,0.f,0.f};

#define STEP(par, t)                                                              \
    {                                                                             \
        /* ---- phase A: layer 0 (K=96) ---- */                                   \
        f16x8 b0 = *(const f16x8*)(xbuf  + (par)*XLAY + bcx);                     \
        f16x8 b1 = *(const f16x8*)(h1buf + ((par)^1)*HLAY + bch);                 \
        f16x8 b2 = *(const f16x8*)(h1buf + ((par)^1)*HLAY + bch + 32);            \
        f32x4 a0 = {0.f,0.f,0.f,0.f}, a1 = a0, a2 = a0, a3 = a0;                  \
        a0 = __builtin_amdgcn_mfma_f32_16x16x32_f16(A0[0][0], b0, a0, 0,0,0);     \
        a1 = __builtin_amdgcn_mfma_f32_16x16x32_f16(A0[1][0], b0, a1, 0,0,0);     \
        a2 = __builtin_amdgcn_mfma_f32_16x16x32_f16(A0[2][0], b0, a2, 0,0,0);     \
        a3 = __builtin_amdgcn_mfma_f32_16x16x32_f16(A0[3][0], b0, a3, 0,0,0);     \
        a0 = __builtin_amdgcn_mfma_f32_16x16x32_f16(A0[0][1], b1, a0, 0,0,0);     \
        a1 = __builtin_amdgcn_mfma_f32_16x16x32_f16(A0[1][1], b1, a1, 0,0,0);     \
        a2 = __builtin_amdgcn_mfma_f32_16x16x32_f16(A0[2][1], b1, a2, 0,0,0);     \
        a3 = __builtin_amdgcn_mfma_f32_16x16x32_f16(A0[3][1], b1, a3, 0,0,0);     \
        a0 = __builtin_amdgcn_mfma_f32_16x16x32_f16(A0[0][2], b2, a0, 0,0,0);     \
        a1 = __builtin_amdgcn_mfma_f32_16x16x32_f16(A0[1][2], b2, a1, 0,0,0);     \
        a2 = __builtin_amdgcn_mfma_f32_16x16x32_f16(A0[2][2], b2, a2, 0,0,0);     \
        a3 = __builtin_amdgcn_mfma_f32_16x16x32_f16(A0[3][2], b2, a3, 0,0,0);     \
        if (xduty) {  /* publish x[t+1], prefetch x[t+2] */                       \
            f16x4 hx; hx[0]=(f16)xpre.x; hx[1]=(f16)xpre.y;                       \
            hx[2]=(f16)xpre.z; hx[3]=(f16)xpre.w;                                 \
            *(f16x4*)(xbuf + ((par)^1)*XLAY + xw_off) = hx;                       \
            int tn = ((t) + 2 < TLEN) ? (t) + 2 : TLEN - 1;                       \
            xpre = *(const float4*)(xg + (long)tn * 32);                          \
        }                                                                         \
        {                                                                         \
            f16x4 hv;                                                             \
            _Pragma("unroll")                                                     \
            for (int r = 0; r < 4; ++r) {                                         \
                float iv = sigf  (a0[r] + bias0[0][r]);                           \
                float fv = sigf  (a1[r] + bias0[1][r]);                           \
                float gv = tanhf_(a2[r] + bias0[2][r]);                           \
                float ov = sigf  (a3[r] + bias0[3][r]);                           \
                c0[r] = fmaf(fv, c0[r], iv * gv);                                 \
                hv[r] = (f16)(ov * tanhf_(c0[r]));                                \
            }                                                                     \
            if (bc < 4) *(f16x4*)(h1buf + (par)*HLAY + hw) = hv;                  \
        }                                                                         \
        __syncthreads();                                                          \
        /* ---- phase B: layer 1 (K=128) ---- */                                  \
        b0 = *(const f16x8*)(h1buf + (par)*HLAY + bch);                           \
        b1 = *(const f16x8*)(h1buf + (par)*HLAY + bch + 32);                      \
        b2 = *(const f16x8*)(h2buf + ((par)^1)*HLAY + bch);                       \
        f16x8 b3 = *(const f16x8*)(h2buf + ((par)^1)*HLAY + bch + 32);            \
        a0 = (f32x4){0.f,0.f,0.f,0.f}; a1 = a0; a2 = a0; a3 = a0;                 \
        a0 = __builtin_amdgcn_mfma_f32_16x16x32_f16(A1[0][0], b0, a0, 0,0,0);     \
        a1 = __builtin_amdgcn_mfma_f32_16x16x32_f16(A1[1][0], b0, a1, 0,0,0);     \
        a2 = __builtin_amdgcn_mfma_f32_16x16x32_f16(A1[2][0], b0, a2, 0,0,0);     \
        a3 = __builtin_amdgcn_mfma_f32_16x16x32_f16(A1[3][0], b0, a3, 0,0,0);     \
        a0 = __builtin_amdgcn_mfma_f32_16x16x32_f16(A1[0][1], b1, a0, 0,0,0);     \
        a1 = __builtin_amdgcn_mfma_f32_16x16x32_f16(A1[1][1], b1, a1, 0,0,0);     \
        a2 = __builtin_amdgcn_mfma_f32_16x16x32_f16(A1[2][1], b1, a2, 0,0,0);     \
        a3 = __builtin_amdgcn_mfma_f32_16x16x32_f16(A1[3][1], b1, a3, 0,0,0);     \
        a0 = __builtin_amdgcn_mfma_f32_16x16x32_f16(A1[0][2], b2, a0, 0,0,0);     \
        a1 = __builtin_amdgcn_mfma_f32_16x16x32_f16(A1[1][2], b2, a1, 0,0,0);     \
        a2 = __builtin_amdgcn_mfma_f32_16x16x32_f16(A1[2][2], b2, a2, 0,0,0);     \
        a3 = __builtin_amdgcn_mfma_f32_16x16x32_f16(A1[3][2], b2, a3, 0,0,0);     \
        a0 = __builtin_amdgcn_mfma_f32_16x16x32_f16(A1[0][3], b3, a0, 0,0,0);     \
        a1 = __builtin_amdgcn_mfma_f32_16x16x32_f16(A1[1][3], b3, a1, 0,0,0);     \
        a2 = __builtin_amdgcn_mfma_f32_16x16x32_f16(A1[2][3], b3, a2, 0,0,0);     \
        a3 = __builtin_amdgcn_mfma_f32_16x16x32_f16(A1[3][3], b3, a3, 0,0,0);     \
        {                                                                         \
            f16x4 hv;                                                             \
            _Pragma("unroll")                                                     \
            for (int r = 0; r < 4; ++r) {                                         \
                float iv = sigf  (a0[r] + bias1[0][r]);                           \
                float fv = sigf  (a1[r] + bias1[1][r]);                           \
                float gv = tanhf_(a2[r] + bias1[2][r]);                           \
                float ov = sigf  (a3[r] + bias1[3][r]);                           \
                c1[r] = fmaf(fv, c1[r], iv * gv);                                 \
                hv[r] = (f16)(ov * tanhf_(c1[r]));                                \
            }                                                                     \
            if (bc < 4) *(f16x4*)(h2buf + (par)*HLAY + hw) = hv;                  \
        }                                                                         \
        __syncthreads();                                                          \
    }

    #pragma unroll 1
    for (int t = 0; t < TLEN; t += 2) {
        STEP(0, t)
        STEP(1, t + 1)
    }
#undef STEP

    // ---- FC head: final h2 is in parity (TLEN-1)&1 = 1 ----
    const f16* h2f = h2buf + HLAY;
    if (tid < 128) {
        int b = tid >> 5, m = tid & 31;
        float z = fc1b[m];
        #pragma unroll
        for (int j = 0; j < 64; ++j)
            z = fmaf(fc1w[m * 64 + j], (float)h2f[b * HSTR + j], z);
        zbuf[b][m] = fmaxf(z, 0.0f);
    }
    __syncthreads();
    if (tid < 8) {
        int b = tid >> 1, o = tid & 1;
        float s = fc2b[o];
        #pragma unroll
        for (int m = 0; m < 32; ++m)
            s = fmaf(fc2w[o * 32 + m], zbuf[b][m], s);
        out[(long)(bg0 + b) * 2 + o] = s;
    }
}

extern "C" void kernel_launch(void* const* d_in, const int* in_sizes, int n_in,
                              void* d_out, int out_size, void* d_ws, size_t ws_size,
                              hipStream_t stream) {
    const float* x    = (const float*)d_in[0];
    const float* Wih0 = (const float*)d_in[1];
    const float* Whh0 = (const float*)d_in[2];
    const float* bih0 = (const float*)d_in[3];
    const float* bhh0 = (const float*)d_in[4];
    const float* Wih1 = (const float*)d_in[5];
    const float* Whh1 = (const float*)d_in[6];
    const float* bih1 = (const float*)d_in[7];
    const float* bhh1 = (const float*)d_in[8];
    const float* fc1w = (const float*)d_in[9];
    const float* fc1b = (const float*)d_in[10];
    const float* fc2w = (const float*)d_in[11];
    const float* fc2b = (const float*)d_in[12];
    float* out = (float*)d_out;

    lstm_fused<<<dim3(NB / 4), dim3(256), 0, stream>>>(
        x, Wih0, Whh0, bih0, bhh0, Wih1, Whh1, bih1, bhh1,
        fc1w, fc1b, fc2w, fc2b, out);
}

// Round 6
// 348.709 us; speedup vs baseline: 6.8532x; 1.5007x over previous
//
#include <hip/hip_runtime.h>
#include <math.h>

#define TLEN 512
#define NB   1024
#define XSTR 40                 // xbuf row stride (f16)
#define HSTR 72                 // h1/h2 row stride (f16)
#define XLAY (16 * XSTR)
#define HLAY (16 * HSTR)
#define SCRW 320                // scratch floats per wave: [lq:80][bc:20][g:4][r:1] -> max 316

typedef _Float16 f16;
typedef f16   f16x4 __attribute__((ext_vector_type(4)));
typedef f16   f16x8 __attribute__((ext_vector_type(8)));
typedef float f32x4 __attribute__((ext_vector_type(4)));

__device__ __forceinline__ float sigf(float x) {
    return __builtin_amdgcn_rcpf(1.0f + __expf(-x));
}
__device__ __forceinline__ float tanhf_(float x) {
    return 2.0f * __builtin_amdgcn_rcpf(1.0f + __expf(-2.0f * x)) - 1.0f;
}

// 256 blocks x 512 threads (8 waves, 2/SIMD). Block owns 4 batches.
// Waves 0-3: layer 0 of step it. Waves 4-7: layer 1 of step it-1 (pipelined).
// Wave wg covers hidden units 16wg..16wg+15, all 4 gates (4 MFMA tiles).
// After MFMA, gates are redistributed through wave-private LDS scratch so each
// lane owns ONE real (hidden,batch) cell -> activation work has zero waste.
// One barrier per pipeline step.
__global__ __launch_bounds__(512, 2) void lstm_fused(
    const float* __restrict__ x,
    const float* __restrict__ Wih0, const float* __restrict__ Whh0,
    const float* __restrict__ bih0, const float* __restrict__ bhh0,
    const float* __restrict__ Wih1, const float* __restrict__ Whh1,
    const float* __restrict__ bih1, const float* __restrict__ bhh1,
    const float* __restrict__ fc1w, const float* __restrict__ fc1b,
    const float* __restrict__ fc2w, const float* __restrict__ fc2b,
    float* __restrict__ out)
{
    __shared__ __align__(16) f16   xbuf[2 * XLAY];
    __shared__ __align__(16) f16   h1buf[2 * HLAY];
    __shared__ __align__(16) f16   h2buf[2 * HLAY];
    __shared__ __align__(16) float scr[8 * SCRW];
    __shared__ float zbuf[4][33];

    const int tid   = threadIdx.x;
    const int lane  = tid & 63;
    const int w     = tid >> 6;          // 0..7
    const int wg    = w & 3;             // hidden group within layer
    const bool isL0 = (w < 4);
    const int bc    = lane & 15;         // MFMA col (batch) / A-row-in-tile
    const int lq    = lane >> 4;         // k-octet / D-row quad
    const int bg0   = blockIdx.x * 4;

    const int h_own = lane >> 2;         // redistributed ownership: hidden (0..15)
    const int b_own = lane & 3;          //                          batch  (0..3)

    // ---- one-time: A-fragments for MY layer (4 gate tiles) ----
    f16x8 A[4][4];
    float bsv[4];
    #pragma unroll
    for (int g = 0; g < 4; ++g) {
        const int gr = g * 64 + 16 * wg + bc;
        #pragma unroll
        for (int s = 0; s < 4; ++s) {
            #pragma unroll
            for (int i = 0; i < 8; ++i) {
                int k = 32 * s + lq * 8 + i;
                float v = 0.0f;
                if (isL0) {
                    if (s < 3) v = (k < 32) ? Wih0[gr * 32 + k] : Whh0[gr * 64 + (k - 32)];
                } else {
                    v = (k < 64) ? Wih1[gr * 64 + k] : Whh1[gr * 64 + (k - 64)];
                }
                A[g][s][i] = (f16)v;
            }
        }
        const int gd = g * 64 + 16 * wg + h_own;
        bsv[g] = isL0 ? (bih0[gd] + bhh0[gd]) : (bih1[gd] + bhh1[gd]);
    }

    // ---- zero LDS (cols >=4 of act buffers stay zero forever) ----
    for (int i = tid; i < 2 * XLAY; i += 512) xbuf[i] = (f16)0;
    for (int i = tid; i < 2 * HLAY; i += 512) { h1buf[i] = (f16)0; h2buf[i] = (f16)0; }
    __syncthreads();

    // ---- x loader: wave 0, lanes 0..31 ----
    const bool xduty = (w == 0) && (lane < 32);
    const int  xbat = lane >> 3, xchk = lane & 7;
    const float* xg = x + ((long)(bg0 + xbat) * TLEN) * 32 + xchk * 4;
    const int xw_off = xbat * XSTR + xchk * 4;
    float4 xpre;
    if (xduty) {
        float4 v = *(const float4*)xg;              // x[0] -> parity 0
        f16x4 h; h[0]=(f16)v.x; h[1]=(f16)v.y; h[2]=(f16)v.z; h[3]=(f16)v.w;
        *(f16x4*)(xbuf + xw_off) = h;
        xpre = *(const float4*)(xg + 32);           // x[1]
    }
    __syncthreads();

    const int bcx   = bc * XSTR + lq * 8;                    // B-frag offsets (f16)
    const int bch   = bc * HSTR + lq * 8;
    const int hwr   = b_own * HSTR + 16 * wg + h_own;        // h write (f16)
    const int swoff = w * SCRW + lq * 80 + bc * 20;          // scratch write (f32)
    const int sroff = w * SCRW + (lane >> 4) * 80 + b_own * 20 + ((lane >> 2) & 3);

    float cst = 0.0f;   // cell state of my (h_own, b_own)

#define CELL_UPDATE(HBUF, PW)                                                 \
    {                                                                         \
        float pi = scr[sroff]      + bsv[0];                                  \
        float pf = scr[sroff + 4]  + bsv[1];                                  \
        float pg = scr[sroff + 8]  + bsv[2];                                  \
        float po = scr[sroff + 12] + bsv[3];                                  \
        float iv = sigf(pi), fv = sigf(pf);                                   \
        float gv = tanhf_(pg), ov = sigf(po);                                 \
        cst = fmaf(fv, cst, iv * gv);                                         \
        HBUF[(PW) * HLAY + hwr] = (f16)(ov * tanhf_(cst));                    \
    }

#define SCR_WRITE()                                                           \
    if (bc < 4) {                                                             \
        *(f32x4*)(scr + swoff)      = a0;                                     \
        *(f32x4*)(scr + swoff + 4)  = a1;                                     \
        *(f32x4*)(scr + swoff + 8)  = a2;                                     \
        *(f32x4*)(scr + swoff + 12) = a3;                                     \
    }

// L0 at iteration it (parity p = it&1): reads xbuf[p], h1buf[p^1]; writes h1buf[p].
#define L0_PHASE(p, itv)                                                      \
    {                                                                         \
        f16x8 b0 = *(const f16x8*)(xbuf  + (p) * XLAY + bcx);                 \
        f16x8 b1 = *(const f16x8*)(h1buf + ((p)^1) * HLAY + bch);             \
        f16x8 b2 = *(const f16x8*)(h1buf + ((p)^1) * HLAY + bch + 32);        \
        f32x4 a0 = {0.f,0.f,0.f,0.f}, a1 = a0, a2 = a0, a3 = a0;              \
        a0 = __builtin_amdgcn_mfma_f32_16x16x32_f16(A[0][0], b0, a0, 0,0,0);  \
        a1 = __builtin_amdgcn_mfma_f32_16x16x32_f16(A[1][0], b0, a1, 0,0,0);  \
        a2 = __builtin_amdgcn_mfma_f32_16x16x32_f16(A[2][0], b0, a2, 0,0,0);  \
        a3 = __builtin_amdgcn_mfma_f32_16x16x32_f16(A[3][0], b0, a3, 0,0,0);  \
        a0 = __builtin_amdgcn_mfma_f32_16x16x32_f16(A[0][1], b1, a0, 0,0,0);  \
        a1 = __builtin_amdgcn_mfma_f32_16x16x32_f16(A[1][1], b1, a1, 0,0,0);  \
        a2 = __builtin_amdgcn_mfma_f32_16x16x32_f16(A[2][1], b1, a2, 0,0,0);  \
        a3 = __builtin_amdgcn_mfma_f32_16x16x32_f16(A[3][1], b1, a3, 0,0,0);  \
        a0 = __builtin_amdgcn_mfma_f32_16x16x32_f16(A[0][2], b2, a0, 0,0,0);  \
        a1 = __builtin_amdgcn_mfma_f32_16x16x32_f16(A[1][2], b2, a1, 0,0,0);  \
        a2 = __builtin_amdgcn_mfma_f32_16x16x32_f16(A[2][2], b2, a2, 0,0,0);  \
        a3 = __builtin_amdgcn_mfma_f32_16x16x32_f16(A[3][2], b2, a3, 0,0,0);  \
        if (xduty) {   /* publish x[it+1], prefetch x[it+2] */                \
            f16x4 hx; hx[0]=(f16)xpre.x; hx[1]=(f16)xpre.y;                   \
            hx[2]=(f16)xpre.z; hx[3]=(f16)xpre.w;                             \
            *(f16x4*)(xbuf + ((p)^1) * XLAY + xw_off) = hx;                   \
            int tn = ((itv) + 2 < TLEN) ? (itv) + 2 : TLEN - 1;               \
            xpre = *(const float4*)(xg + (long)tn * 32);                      \
        }                                                                     \
        SCR_WRITE()                                                           \
        CELL_UPDATE(h1buf, p)                                                 \
    }

// L1 at iteration it (t = it-1, p = it&1): reads h1buf[p^1] (=h1[t]),
// h2buf[p] (=h2[t-1]); writes h2buf[p^1] (=h2[t]).
#define L1_PHASE(p)                                                           \
    {                                                                         \
        f16x8 b0 = *(const f16x8*)(h1buf + ((p)^1) * HLAY + bch);             \
        f16x8 b1 = *(const f16x8*)(h1buf + ((p)^1) * HLAY + bch + 32);        \
        f16x8 b2 = *(const f16x8*)(h2buf + (p) * HLAY + bch);                 \
        f16x8 b3 = *(const f16x8*)(h2buf + (p) * HLAY + bch + 32);            \
        f32x4 a0 = {0.f,0.f,0.f,0.f}, a1 = a0, a2 = a0, a3 = a0;              \
        a0 = __builtin_amdgcn_mfma_f32_16x16x32_f16(A[0][0], b0, a0, 0,0,0);  \
        a1 = __builtin_amdgcn_mfma_f32_16x16x32_f16(A[1][0], b0, a1, 0,0,0);  \
        a2 = __builtin_amdgcn_mfma_f32_16x16x32_f16(A[2][0], b0, a2, 0,0,0);  \
        a3 = __builtin_amdgcn_mfma_f32_16x16x32_f16(A[3][0], b0, a3, 0,0,0);  \
        a0 = __builtin_amdgcn_mfma_f32_16x16x32_f16(A[0][1], b1, a0, 0,0,0);  \
        a1 = __builtin_amdgcn_mfma_f32_16x16x32_f16(A[1][1], b1, a1, 0,0,0);  \
        a2 = __builtin_amdgcn_mfma_f32_16x16x32_f16(A[2][1], b1, a2, 0,0,0);  \
        a3 = __builtin_amdgcn_mfma_f32_16x16x32_f16(A[3][1], b1, a3, 0,0,0);  \
        a0 = __builtin_amdgcn_mfma_f32_16x16x32_f16(A[0][2], b2, a0, 0,0,0);  \
        a1 = __builtin_amdgcn_mfma_f32_16x16x32_f16(A[1][2], b2, a1, 0,0,0);  \
        a2 = __builtin_amdgcn_mfma_f32_16x16x32_f16(A[2][2], b2, a2, 0,0,0);  \
        a3 = __builtin_amdgcn_mfma_f32_16x16x32_f16(A[3][2], b2, a3, 0,0,0);  \
        a0 = __builtin_amdgcn_mfma_f32_16x16x32_f16(A[0][3], b3, a0, 0,0,0);  \
        a1 = __builtin_amdgcn_mfma_f32_16x16x32_f16(A[1][3], b3, a1, 0,0,0);  \
        a2 = __builtin_amdgcn_mfma_f32_16x16x32_f16(A[2][3], b3, a2, 0,0,0);  \
        a3 = __builtin_amdgcn_mfma_f32_16x16x32_f16(A[3][3], b3, a3, 0,0,0);  \
        SCR_WRITE()                                                           \
        CELL_UPDATE(h2buf, (p)^1)                                             \
    }

    // ---- pipeline: it = 0 .. 512 ----
    if (isL0) L0_PHASE(0, 0)            // it = 0
    __syncthreads();

    #pragma unroll 1
    for (int k = 0; k < 255; ++k) {     // it = 2k+1, 2k+2  (1..510)
        if (isL0) L0_PHASE(1, 2 * k + 1) else L1_PHASE(1)
        __syncthreads();
        if (isL0) L0_PHASE(0, 2 * k + 2) else L1_PHASE(0)
        __syncthreads();
    }

    if (isL0) L0_PHASE(1, 511) else L1_PHASE(1)   // it = 511
    __syncthreads();
    if (!isL0) L1_PHASE(0)                        // it = 512 (L1 finishes h2[511])
    __syncthreads();

#undef L0_PHASE
#undef L1_PHASE
#undef SCR_WRITE
#undef CELL_UPDATE

    // ---- FC head: h2[511] is in parity 1 ----
    const f16* h2f = h2buf + HLAY;
    if (tid < 128) {
        int b = tid >> 5, m = tid & 31;
        float z = fc1b[m];
        #pragma unroll
        for (int j = 0; j < 64; ++j)
            z = fmaf(fc1w[m * 64 + j], (float)h2f[b * HSTR + j], z);
        zbuf[b][m] = fmaxf(z, 0.0f);
    }
    __syncthreads();
    if (tid < 8) {
        int b = tid >> 1, o = tid & 1;
        float s = fc2b[o];
        #pragma unroll
        for (int m = 0; m < 32; ++m)
            s = fmaf(fc2w[o * 32 + m], zbuf[b][m], s);
        out[(long)(bg0 + b) * 2 + o] = s;
    }
}

extern "C" void kernel_launch(void* const* d_in, const int* in_sizes, int n_in,
                              void* d_out, int out_size, void* d_ws, size_t ws_size,
                              hipStream_t stream) {
    const float* x    = (const float*)d_in[0];
    const float* Wih0 = (const float*)d_in[1];
    const float* Whh0 = (const float*)d_in[2];
    const float* bih0 = (const float*)d_in[3];
    const float* bhh0 = (const float*)d_in[4];
    const float* Wih1 = (const float*)d_in[5];
    const float* Whh1 = (const float*)d_in[6];
    const float* bih1 = (const float*)d_in[7];
    const float* bhh1 = (const float*)d_in[8];
    const float* fc1w = (const float*)d_in[9];
    const float* fc1b = (const float*)d_in[10];
    const float* fc2w = (const float*)d_in[11];
    const float* fc2b = (const float*)d_in[12];
    float* out = (float*)d_out;

    lstm_fused<<<dim3(NB / 4), dim3(512), 0, stream>>>(
        x, Wih0, Whh0, bih0, bhh0, Wih1, Whh1, bih1, bhh1,
        fc1w, fc1b, fc2w, fc2b, out);
}

// Round 7
// 242.888 us; speedup vs baseline: 9.8391x; 1.4357x over previous
//
#include <hip/hip_runtime.h>
#include <math.h>

#define TLEN 512
#define NB   1024
#define XSTR 48                 // xbuf row stride (f16): 24 dwords ≡ 24 mod 32 -> 2-way max
#define HSTR 80                 // h buf row stride (f16): 40 dwords ≡ 8 mod 32 -> 2-way max
#define XLAY (4 * XSTR)         // 4 batch rows per parity
#define HLAY (4 * HSTR)

typedef _Float16 f16;
typedef f16   f16x4 __attribute__((ext_vector_type(4)));
typedef f16   f16x8 __attribute__((ext_vector_type(8)));
typedef float f32x4 __attribute__((ext_vector_type(4)));

__device__ __forceinline__ float sigf(float x) {
    return __builtin_amdgcn_rcpf(1.0f + __expf(-x));
}
__device__ __forceinline__ float tanhf_(float x) {
    return 2.0f * __builtin_amdgcn_rcpf(1.0f + __expf(-2.0f * x)) - 1.0f;
}
// compile-time-indexed select of v[g], g in 0..3 (3 cndmask, no scratch)
__device__ __forceinline__ float sel4(f32x4 v, int g) {
    float a = (g & 1) ? v[1] : v[0];
    float b = (g & 1) ? v[3] : v[2];
    return (g & 2) ? b : a;
}

// 256 blocks x 512 threads (8 waves, 2/SIMD). Block owns 4 batches.
// Waves 0-3: layer 0 of step it. Waves 4-7: layer 1 of step it-1 (pipelined).
// Wave wg covers hidden units 16wg..16wg+15, all 4 gates (4 MFMA tiles).
// B-fragments are BROADCAST reads: lane bc reads batch (bc&3)'s activations, so
// MFMA cols 4-15 hold duplicates of cols 0-3. Lane group G=bc>>2 then consumes
// accumulator reg r=G -> each lane owns ONE real (hidden,batch) cell entirely
// in registers: no gate redistribution through LDS at all.
__global__ __launch_bounds__(512, 2) void lstm_fused(
    const float* __restrict__ x,
    const float* __restrict__ Wih0, const float* __restrict__ Whh0,
    const float* __restrict__ bih0, const float* __restrict__ bhh0,
    const float* __restrict__ Wih1, const float* __restrict__ Whh1,
    const float* __restrict__ bih1, const float* __restrict__ bhh1,
    const float* __restrict__ fc1w, const float* __restrict__ fc1b,
    const float* __restrict__ fc2w, const float* __restrict__ fc2b,
    float* __restrict__ out)
{
    __shared__ __align__(16) f16 xbuf[2 * XLAY];
    __shared__ __align__(16) f16 h1buf[2 * HLAY];
    __shared__ __align__(16) f16 h2buf[2 * HLAY];
    __shared__ float zbuf[4][33];

    const int tid   = threadIdx.x;
    const int lane  = tid & 63;
    const int w     = tid >> 6;          // 0..7
    const int wg    = w & 3;             // hidden group within layer
    const bool isL0 = (w < 4);
    const int bc    = lane & 15;         // MFMA col / A-row-in-tile
    const int lq    = lane >> 4;         // k-octet / D-row quad
    const int G     = bc >> 2;           // copy-group -> which acc reg this lane consumes
    const int b_own = bc & 3;            // batch this lane's column carries
    const int bg0   = blockIdx.x * 4;

    // ---- one-time: A-fragments for MY layer (4 gate tiles) ----
    f16x8 A[4][4];
    float bsv[4];
    #pragma unroll
    for (int g = 0; g < 4; ++g) {
        const int gr = g * 64 + 16 * wg + bc;
        #pragma unroll
        for (int s = 0; s < 4; ++s) {
            #pragma unroll
            for (int i = 0; i < 8; ++i) {
                int k = 32 * s + lq * 8 + i;
                float v = 0.0f;
                if (isL0) {
                    if (s < 3) v = (k < 32) ? Wih0[gr * 32 + k] : Whh0[gr * 64 + (k - 32)];
                } else {
                    v = (k < 64) ? Wih1[gr * 64 + k] : Whh1[gr * 64 + (k - 64)];
                }
                A[g][s][i] = (f16)v;
            }
        }
        const int gd = g * 64 + 16 * wg + 4 * lq + G;   // my cell's gate row
        bsv[g] = isL0 ? (bih0[gd] + bhh0[gd]) : (bih1[gd] + bhh1[gd]);
    }

    // ---- zero LDS ----
    for (int i = tid; i < 2 * XLAY; i += 512) xbuf[i] = (f16)0;
    for (int i = tid; i < 2 * HLAY; i += 512) { h1buf[i] = (f16)0; h2buf[i] = (f16)0; }
    __syncthreads();

    // ---- x loader: wave 0, lanes 0..31 ----
    const bool xduty = (w == 0) && (lane < 32);
    const int  xbat = lane >> 3, xchk = lane & 7;
    const float* xg = x + ((long)(bg0 + xbat) * TLEN) * 32 + xchk * 4;
    const int xw_off = xbat * XSTR + xchk * 4;
    float4 xpre;
    if (xduty) {
        float4 v = *(const float4*)xg;              // x[0] -> parity 0
        f16x4 h; h[0]=(f16)v.x; h[1]=(f16)v.y; h[2]=(f16)v.z; h[3]=(f16)v.w;
        *(f16x4*)(xbuf + xw_off) = h;
        xpre = *(const float4*)(xg + 32);           // x[1]
    }
    __syncthreads();

    const int bcx = b_own * XSTR + lq * 8;                 // broadcast B-frag offsets
    const int bch = b_own * HSTR + lq * 8;
    const int hwr = b_own * HSTR + 16 * wg + 4 * lq + G;   // h write (64 distinct f16/wave)

    float cst = 0.0f;   // cell state of my (16wg+4lq+G, b_own)

#define CELL_UPDATE(HBUF, PW)                                                 \
    {                                                                         \
        float pi = sel4(a0, G) + bsv[0];                                      \
        float pf = sel4(a1, G) + bsv[1];                                      \
        float pg = sel4(a2, G) + bsv[2];                                      \
        float po = sel4(a3, G) + bsv[3];                                      \
        float iv = sigf(pi), fv = sigf(pf);                                   \
        float gv = tanhf_(pg), ov = sigf(po);                                 \
        cst = fmaf(fv, cst, iv * gv);                                         \
        HBUF[(PW) * HLAY + hwr] = (f16)(ov * tanhf_(cst));                    \
    }

// L0 at iteration it (parity p = it&1): reads xbuf[p], h1buf[p^1]; writes h1buf[p].
#define L0_PHASE(p, itv)                                                      \
    {                                                                         \
        f16x8 b0 = *(const f16x8*)(xbuf  + (p) * XLAY + bcx);                 \
        f16x8 b1 = *(const f16x8*)(h1buf + ((p)^1) * HLAY + bch);             \
        f16x8 b2 = *(const f16x8*)(h1buf + ((p)^1) * HLAY + bch + 32);        \
        f32x4 a0 = {0.f,0.f,0.f,0.f}, a1 = a0, a2 = a0, a3 = a0;              \
        a0 = __builtin_amdgcn_mfma_f32_16x16x32_f16(A[0][0], b0, a0, 0,0,0);  \
        a1 = __builtin_amdgcn_mfma_f32_16x16x32_f16(A[1][0], b0, a1, 0,0,0);  \
        a2 = __builtin_amdgcn_mfma_f32_16x16x32_f16(A[2][0], b0, a2, 0,0,0);  \
        a3 = __builtin_amdgcn_mfma_f32_16x16x32_f16(A[3][0], b0, a3, 0,0,0);  \
        a0 = __builtin_amdgcn_mfma_f32_16x16x32_f16(A[0][1], b1, a0, 0,0,0);  \
        a1 = __builtin_amdgcn_mfma_f32_16x16x32_f16(A[1][1], b1, a1, 0,0,0);  \
        a2 = __builtin_amdgcn_mfma_f32_16x16x32_f16(A[2][1], b1, a2, 0,0,0);  \
        a3 = __builtin_amdgcn_mfma_f32_16x16x32_f16(A[3][1], b1, a3, 0,0,0);  \
        a0 = __builtin_amdgcn_mfma_f32_16x16x32_f16(A[0][2], b2, a0, 0,0,0);  \
        a1 = __builtin_amdgcn_mfma_f32_16x16x32_f16(A[1][2], b2, a1, 0,0,0);  \
        a2 = __builtin_amdgcn_mfma_f32_16x16x32_f16(A[2][2], b2, a2, 0,0,0);  \
        a3 = __builtin_amdgcn_mfma_f32_16x16x32_f16(A[3][2], b2, a3, 0,0,0);  \
        if (xduty) {   /* publish x[it+1], prefetch x[it+2] */                \
            f16x4 hx; hx[0]=(f16)xpre.x; hx[1]=(f16)xpre.y;                   \
            hx[2]=(f16)xpre.z; hx[3]=(f16)xpre.w;                             \
            *(f16x4*)(xbuf + ((p)^1) * XLAY + xw_off) = hx;                   \
            int tn = ((itv) + 2 < TLEN) ? (itv) + 2 : TLEN - 1;               \
            xpre = *(const float4*)(xg + (long)tn * 32);                      \
        }                                                                     \
        CELL_UPDATE(h1buf, p)                                                 \
    }

// L1 at iteration it (t = it-1, p = it&1): reads h1buf[p^1] (=h1[t]),
// h2buf[p] (=h2[t-1]); writes h2buf[p^1] (=h2[t]).
#define L1_PHASE(p)                                                           \
    {                                                                         \
        f16x8 b0 = *(const f16x8*)(h1buf + ((p)^1) * HLAY + bch);             \
        f16x8 b1 = *(const f16x8*)(h1buf + ((p)^1) * HLAY + bch + 32);        \
        f16x8 b2 = *(const f16x8*)(h2buf + (p) * HLAY + bch);                 \
        f16x8 b3 = *(const f16x8*)(h2buf + (p) * HLAY + bch + 32);            \
        f32x4 a0 = {0.f,0.f,0.f,0.f}, a1 = a0, a2 = a0, a3 = a0;              \
        a0 = __builtin_amdgcn_mfma_f32_16x16x32_f16(A[0][0], b0, a0, 0,0,0);  \
        a1 = __builtin_amdgcn_mfma_f32_16x16x32_f16(A[1][0], b0, a1, 0,0,0);  \
        a2 = __builtin_amdgcn_mfma_f32_16x16x32_f16(A[2][0], b0, a2, 0,0,0);  \
        a3 = __builtin_amdgcn_mfma_f32_16x16x32_f16(A[3][0], b0, a3, 0,0,0);  \
        a0 = __builtin_amdgcn_mfma_f32_16x16x32_f16(A[0][1], b1, a0, 0,0,0);  \
        a1 = __builtin_amdgcn_mfma_f32_16x16x32_f16(A[1][1], b1, a1, 0,0,0);  \
        a2 = __builtin_amdgcn_mfma_f32_16x16x32_f16(A[2][1], b1, a2, 0,0,0);  \
        a3 = __builtin_amdgcn_mfma_f32_16x16x32_f16(A[3][1], b1, a3, 0,0,0);  \
        a0 = __builtin_amdgcn_mfma_f32_16x16x32_f16(A[0][2], b2, a0, 0,0,0);  \
        a1 = __builtin_amdgcn_mfma_f32_16x16x32_f16(A[1][2], b2, a1, 0,0,0);  \
        a2 = __builtin_amdgcn_mfma_f32_16x16x32_f16(A[2][2], b2, a2, 0,0,0);  \
        a3 = __builtin_amdgcn_mfma_f32_16x16x32_f16(A[3][2], b2, a3, 0,0,0);  \
        a0 = __builtin_amdgcn_mfma_f32_16x16x32_f16(A[0][3], b3, a0, 0,0,0);  \
        a1 = __builtin_amdgcn_mfma_f32_16x16x32_f16(A[1][3], b3, a1, 0,0,0);  \
        a2 = __builtin_amdgcn_mfma_f32_16x16x32_f16(A[2][3], b3, a2, 0,0,0);  \
        a3 = __builtin_amdgcn_mfma_f32_16x16x32_f16(A[3][3], b3, a3, 0,0,0);  \
        CELL_UPDATE(h2buf, (p)^1)                                             \
    }

    // ---- pipeline: it = 0 .. 512 ----
    if (isL0) L0_PHASE(0, 0)            // it = 0
    __syncthreads();

    #pragma unroll 1
    for (int k = 0; k < 255; ++k) {     // it = 2k+1, 2k+2  (1..510)
        if (isL0) L0_PHASE(1, 2 * k + 1) else L1_PHASE(1)
        __syncthreads();
        if (isL0) L0_PHASE(0, 2 * k + 2) else L1_PHASE(0)
        __syncthreads();
    }

    if (isL0) L0_PHASE(1, 511) else L1_PHASE(1)   // it = 511
    __syncthreads();
    if (!isL0) L1_PHASE(0)                        // it = 512 (L1 finishes h2[511])
    __syncthreads();

#undef L0_PHASE
#undef L1_PHASE
#undef CELL_UPDATE

    // ---- FC head: h2[511] is in parity 1 ----
    const f16* h2f = h2buf + HLAY;
    if (tid < 128) {
        int b = tid >> 5, m = tid & 31;
        float z = fc1b[m];
        #pragma unroll
        for (int j = 0; j < 64; ++j)
            z = fmaf(fc1w[m * 64 + j], (float)h2f[b * HSTR + j], z);
        zbuf[b][m] = fmaxf(z, 0.0f);
    }
    __syncthreads();
    if (tid < 8) {
        int b = tid >> 1, o = tid & 1;
        float s = fc2b[o];
        #pragma unroll
        for (int m = 0; m < 32; ++m)
            s = fmaf(fc2w[o * 32 + m], zbuf[b][m], s);
        out[(long)(bg0 + b) * 2 + o] = s;
    }
}

extern "C" void kernel_launch(void* const* d_in, const int* in_sizes, int n_in,
                              void* d_out, int out_size, void* d_ws, size_t ws_size,
                              hipStream_t stream) {
    const float* x    = (const float*)d_in[0];
    const float* Wih0 = (const float*)d_in[1];
    const float* Whh0 = (const float*)d_in[2];
    const float* bih0 = (const float*)d_in[3];
    const float* bhh0 = (const float*)d_in[4];
    const float* Wih1 = (const float*)d_in[5];
    const float* Whh1 = (const float*)d_in[6];
    const float* bih1 = (const float*)d_in[7];
    const float* bhh1 = (const float*)d_in[8];
    const float* fc1w = (const float*)d_in[9];
    const float* fc1b = (const float*)d_in[10];
    const float* fc2w = (const float*)d_in[11];
    const float* fc2b = (const float*)d_in[12];
    float* out = (float*)d_out;

    lstm_fused<<<dim3(NB / 4), dim3(512), 0, stream>>>(
        x, Wih0, Whh0, bih0, bhh0, Wih1, Whh1, bih1, bhh1,
        fc1w, fc1b, fc2w, fc2b, out);
}